// Round 1
// baseline (292.481 us; speedup 1.0000x reference)
//
#include <hip/hip_runtime.h>

#define TS 20        // states
#define TT 400       // T*T
#define NB 128       // batch
#define NL 512       // seq len
#define HALF 256     // fwd/bwd split point
#define S_START 17
#define S_END 18

// ws float-index layout:
//  [0]  gold energy accumulator (atomic)
//  [8]  (int) mask_is_u8 flag
//  [9]  (int) gold_is_i64 flag
//  [16..144)    fwd s per batch
//  [160..2720)  fwd lq per batch*20
//  [2720..2848) bwd s
//  [2848..5408) bwd lq
#define WS_GOLD 0
#define WS_FMASK 8
#define WS_FG64 9
#define WS_FS 16
#define WS_FL 160
#define WS_BS 2720
#define WS_BL 2848

__device__ __forceinline__ float rfl_f(float x) {
    return __int_as_float(__builtin_amdgcn_readfirstlane(__float_as_int(x)));
}

// --- detector + accumulator init -------------------------------------------
__global__ void crf_init(const unsigned char* __restrict__ mask8,
                         const int* __restrict__ gold32,
                         float* __restrict__ wsf, int* __restrict__ wsi) {
    if (threadIdx.x == 0) {
        wsf[WS_GOLD] = 0.0f;
        // mask row 0 is all-true (len>=1). If stored as u8, byte 1 == 1.
        // If stored as i32/f32, byte 1 is the 2nd byte of element 0 -> 0.
        wsi[WS_FMASK] = (mask8[1] == 1) ? 1 : 0;
        // gold values < 400. If i64, every odd 32-bit word is 0.
        int o = 0;
        for (int k = 1; k < 32; k += 2) o |= gold32[k];
        wsi[WS_FG64] = (o == 0) ? 1 : 0;
    }
}

// --- gold energy: masked gather-sum ----------------------------------------
__global__ __launch_bounds__(256) void crf_gold(const float* __restrict__ tr,
                                                const unsigned char* __restrict__ mask8,
                                                const int* __restrict__ mask32,
                                                const int* __restrict__ gold32,
                                                float* __restrict__ wsf,
                                                const int* __restrict__ wsi) {
    const int idx = blockIdx.x * 256 + threadIdx.x;   // l*128+b, < 65536
    const int isu8 = wsi[WS_FMASK];
    const int is64 = wsi[WS_FG64];
    int m = isu8 ? (int)mask8[idx] : mask32[idx];
    float v = 0.0f;
    if (m) {
        int g = is64 ? gold32[2 * idx] : gold32[idx];
        g = max(0, min(g, TT - 1));   // crash guard if dtype misdetected
        v = tr[(size_t)idx * TT + g];
    }
    #pragma unroll
    for (int off = 32; off; off >>= 1) v += __shfl_down(v, off);
    __shared__ float ps[4];
    if ((threadIdx.x & 63) == 0) ps[threadIdx.x >> 6] = v;
    __syncthreads();
    if (threadIdx.x == 0) atomicAdd(wsf + WS_GOLD, ps[0] + ps[1] + ps[2] + ps[3]);
}

// --- chain helpers ----------------------------------------------------------
__device__ __forceinline__ void load_tile(const float* __restrict__ tr, int lrow,
                                          int b, int lane, float4& A, float4& B) {
    const float4* tp = (const float4*)(tr + (size_t)(lrow * NB + b) * TT);
    A = tp[lane];                      // f4 idx lane (<100)
    if (lane < 36) B = tp[64 + lane];  // f4 idx 64+lane (<100)
}

__device__ __forceinline__ void stage4(float* __restrict__ bufn, int n0, float4 v, int dir) {
    const float* vf = (const float*)&v;
    #pragma unroll
    for (int c = 0; c < 4; ++c) {
        int n = n0 + c;           // element i*20+j
        int i = n / TS;
        int j = n - i * TS;
        float x = vf[c] + ((j < 4) ? 1.0f : 0.0f);   // CHEM cost on "to" state
        float w = __expf(x);
        bufn[(dir == 0) ? (j * TS + i) : n] = w;     // fwd: transposed
    }
}

__device__ __forceinline__ void stage_tile(float* __restrict__ bufn, int lane, int dir,
                                           float4 A, float4 B) {
    stage4(bufn, 4 * lane, A, dir);
    if (lane < 36) stage4(bufn, 4 * (64 + lane), B, dir);
}

__device__ __forceinline__ void chain_step(const float* __restrict__ bufc, int jc,
                                           float* qs, float& s, float& q) {
    const float4* rp = (const float4*)(bufc) + jc * 5;  // row jc: 20 floats
    float4 w0 = rp[0], w1 = rp[1], w2 = rp[2], w3 = rp[3], w4 = rp[4];
    float a0 = qs[0] * w0.x;
    float a1 = qs[1] * w0.y;
    float a2 = qs[2] * w0.z;
    float a3 = qs[3] * w0.w;
    a0 = fmaf(qs[4],  w1.x, a0);  a1 = fmaf(qs[5],  w1.y, a1);
    a2 = fmaf(qs[6],  w1.z, a2);  a3 = fmaf(qs[7],  w1.w, a3);
    a0 = fmaf(qs[8],  w2.x, a0);  a1 = fmaf(qs[9],  w2.y, a1);
    a2 = fmaf(qs[10], w2.z, a2);  a3 = fmaf(qs[11], w2.w, a3);
    a0 = fmaf(qs[12], w3.x, a0);  a1 = fmaf(qs[13], w3.y, a1);
    a2 = fmaf(qs[14], w3.z, a2);  a3 = fmaf(qs[15], w3.w, a3);
    a0 = fmaf(qs[16], w4.x, a0);  a1 = fmaf(qs[17], w4.y, a1);
    a2 = fmaf(qs[18], w4.z, a2);  a3 = fmaf(qs[19], w4.w, a3);
    float acc = (a0 + a1) + (a2 + a3);
    // exponent-only renormalization: rebase by 2^e of lane 0's acc
    int ebits = __builtin_amdgcn_readfirstlane(__float_as_int(acc));
    int e = ((ebits >> 23) & 255) - 127;
    s += (float)e * 0.6931471805599453f;
    float scale = __int_as_float((127 - e) << 23);   // 2^-e exactly
    q = acc * scale;
    #pragma unroll
    for (int i = 0; i < TS; ++i)
        qs[i] = __int_as_float(__builtin_amdgcn_readlane(__float_as_int(q), i));
}

// --- main scan: 256 blocks = 128 batches x {fwd,bwd}, 1 wave each -----------
__global__ __launch_bounds__(64) void crf_chain(const float* __restrict__ tr,
                                                const unsigned char* __restrict__ mask8,
                                                const int* __restrict__ mask32,
                                                float* __restrict__ wsf,
                                                const int* __restrict__ wsi) {
    const int lane = threadIdx.x;
    const int b = blockIdx.x >> 1;
    const int dir = blockIdx.x & 1;   // 0 = forward, 1 = backward
    __shared__ float buf[2 * TT];

    // ---- sequence length from mask column b (mask is monotone per column)
    int cnt = 0;
    if (wsi[WS_FMASK]) {
        #pragma unroll
        for (int t = 0; t < 8; ++t) cnt += mask8[(lane + 64 * t) * NB + b] ? 1 : 0;
    } else {
        #pragma unroll
        for (int t = 0; t < 8; ++t) cnt += mask32[(lane + 64 * t) * NB + b] ? 1 : 0;
    }
    #pragma unroll
    for (int off = 1; off < 64; off <<= 1) cnt += __shfl_xor(cnt, off);
    int len = max(1, min(cnt, NL));

    // ---- state init
    const int jc = (lane < TS - 1) ? lane : (TS - 1);
    float s, lq, q;
    if (dir == 0) {
        float t0 = tr[(size_t)b * TT + S_START * TS + jc];  // row l=0, from=START
        float ref = rfl_f(t0);
        s = ref; lq = t0 - ref; q = __expf(lq);
    } else {
        s = 0.0f;
        lq = (jc == S_END) ? 0.0f : -1e30f;
        q  = (jc == S_END) ? 1.0f : 0.0f;
    }
    float qs[TS];
    #pragma unroll
    for (int i = 0; i < TS; ++i)
        qs[i] = __int_as_float(__builtin_amdgcn_readlane(__float_as_int(q), i));

    const int S = (dir == 0) ? ((len < HALF ? len : HALF) - 1)
                             : (len > HALF ? len - HALF : 0);

    if (S > 0) {
        float4 zz = make_float4(0, 0, 0, 0);
        float4 A0 = zz, B0 = zz, A1 = zz, B1 = zz, A2 = zz, B2 = zz;
        float4 A3 = zz, B3 = zz, A4 = zz, B4 = zz, A5 = zz, B5 = zz;
        #define LROW(u) ((dir == 0) ? (1 + (u)) : (len - 1 - (u)))
        load_tile(tr, LROW(0), b, lane, A0, B0);
        stage_tile(buf, lane, dir, A0, B0);                 // tile 0 -> buf0
        if (S > 1) load_tile(tr, LROW(1), b, lane, A1, B1);
        if (S > 2) load_tile(tr, LROW(2), b, lane, A2, B2);
        if (S > 3) load_tile(tr, LROW(3), b, lane, A3, B3);
        if (S > 4) load_tile(tr, LROW(4), b, lane, A4, B4);
        if (S > 5) load_tile(tr, LROW(5), b, lane, A5, B5);

        #define STEP(u, LA, LB, SA, SB)                                          \
            if ((u) < S) {                                                       \
                if ((u) + 6 < S) load_tile(tr, LROW((u) + 6), b, lane, LA, LB);  \
                chain_step(buf + (((u) & 1) * TT), jc, qs, s, q);                \
                if ((u) + 1 < S)                                                 \
                    stage_tile(buf + ((((u) + 1) & 1) * TT), lane, dir, SA, SB); \
            }

        for (int t = 0; t < S; t += 6) {
            STEP(t + 0, A0, B0, A1, B1);
            STEP(t + 1, A1, B1, A2, B2);
            STEP(t + 2, A2, B2, A3, B3);
            STEP(t + 3, A3, B3, A4, B4);
            STEP(t + 4, A4, B4, A5, B5);
            STEP(t + 5, A5, B5, A0, B0);
        }
        lq = __logf(q);
        #undef STEP
        #undef LROW
    }

    // ---- write (s, lq[20]) for merge
    float* ss = wsf + ((dir == 0) ? WS_FS : WS_BS);
    float* ll = wsf + ((dir == 0) ? WS_FL : WS_BL);
    if (lane == 0) ss[b] = s;
    if (lane < TS) ll[b * TS + lane] = lq;
}

// --- merge fwd x bwd + gold, write loss -------------------------------------
__global__ __launch_bounds__(128) void crf_merge(const float* __restrict__ wsf,
                                                 float* __restrict__ out) {
    const int b = threadIdx.x;   // 128 threads = 128 batches
    const float* fl = wsf + WS_FL + b * TS;
    const float* bl = wsf + WS_BL + b * TS;
    float v[TS];
    float m = -3e38f;
    #pragma unroll
    for (int i = 0; i < TS; ++i) { v[i] = fl[i] + bl[i]; m = fmaxf(m, v[i]); }
    float sum = 0.0f;
    #pragma unroll
    for (int i = 0; i < TS; ++i) sum += __expf(v[i] - m);
    float part = wsf[WS_FS + b] + wsf[WS_BS + b] + m + __logf(sum);
    #pragma unroll
    for (int off = 32; off; off >>= 1) part += __shfl_down(part, off);
    __shared__ float ps[2];
    if ((threadIdx.x & 63) == 0) ps[threadIdx.x >> 6] = part;
    __syncthreads();
    if (threadIdx.x == 0) out[0] = (ps[0] + ps[1] - wsf[WS_GOLD]) / 128.0f;
}

extern "C" void kernel_launch(void* const* d_in, const int* in_sizes, int n_in,
                              void* d_out, int out_size, void* d_ws, size_t ws_size,
                              hipStream_t stream) {
    const float* tr = (const float*)d_in[0];
    const int* gold32 = (const int*)d_in[1];
    const unsigned char* mask8 = (const unsigned char*)d_in[2];
    const int* mask32 = (const int*)d_in[2];
    float* wsf = (float*)d_ws;
    int* wsi = (int*)d_ws;
    float* out = (float*)d_out;

    crf_init<<<1, 64, 0, stream>>>(mask8, gold32, wsf, wsi);
    crf_gold<<<256, 256, 0, stream>>>(tr, mask8, mask32, gold32, wsf, wsi);
    crf_chain<<<256, 64, 0, stream>>>(tr, mask8, mask32, wsf, wsi);
    crf_merge<<<1, 128, 0, stream>>>(wsf, out);
}